// Round 1
// 1826.961 us; speedup vs baseline: 10.3743x; 10.3743x over previous
//
#include <hip/hip_runtime.h>
#include <hip/hip_bf16.h>
#include <cstdint>
#include <cstddef>

// Swin block: B=32 H=W=56 C=384 NH=12 HD=32 WS=7 SS=3 N=49 NW=64 Bn=2048 HID=1536
// M = 100352 tokens. All external I/O f32; internals bf16 storage + f32/MFMA accum.
//
// d_out (154,140,672 B) scratch aliases:
//   H0 = [0, 77070336)          : attnout bf16 (100352x384)   [dead after proj]
//   H1 = [77070336, 154140672)  : winbuf bf16 -> xmid bf16    [winbuf dead after qkv]
// Final f32 output overwrites d_out chunk-by-chunk; stomp-free schedule:
//   fc2 chunk c (12544 rows) write stomps xmid rows [25088(c-4), +25088), all
//   consumed by earlier chunks; only chunk 7's 2nd half self-stomps -> resb copy.
//
// ws layout (49,774,592 B):
//   [0,        802816)   ln2 stats (mean,rstd f32 per token)
//   [802816,  1687552)   qkv_wt  bf16 1152x384 (N-major, transposed)
//   [1687552, 1982464)   proj_wt bf16  384x384
//   [1982464, 3162112)   fc1_wt  bf16 1536x384
//   [3162112, 4341760)   fc2_wt  bf16  384x1536
//   [4341760, ...)       shared: qkvbuf bf16 12544x1152 (attn phase)
//                              / hbuf bf16 12544x1536 + resb 6272x384 (MLP phase)

typedef __attribute__((ext_vector_type(8))) short bf16x8;
typedef __attribute__((ext_vector_type(4))) float f32x4;

__device__ __forceinline__ float bf2f(__hip_bfloat16 x) { return __bfloat162float(x); }
__device__ __forceinline__ __hip_bfloat16 f2bf(float x) { return __float2bfloat16(x); }
__device__ __forceinline__ float s2f(short s) {
    unsigned u = ((unsigned)(unsigned short)s) << 16;
    return __builtin_bit_cast(float, u);
}
__device__ __forceinline__ short f2s(float f) {
    __hip_bfloat16 h = __float2bfloat16(f);
    return (short)__builtin_bit_cast(unsigned short, h);
}
__device__ __forceinline__ float gelu_exact(float x) {
    return 0.5f * x * (1.0f + erff(x * 0.70710678118654752f));
}

// ---------------- LN2 stats: per token mean/rstd over 384 channels (bf16 in) ----
__global__ __launch_bounds__(256)
void ln_stats_bf16(const __hip_bfloat16* __restrict__ src, float* __restrict__ stats)
{
    int t = blockIdx.x * 4 + (threadIdx.x >> 6);
    int lane = threadIdx.x & 63;
    const __hip_bfloat16* p = src + (size_t)t * 384 + lane * 6;
    float s = 0.f, s2 = 0.f;
#pragma unroll
    for (int u = 0; u < 6; ++u) { float f = bf2f(p[u]); s += f; s2 += f * f; }
#pragma unroll
    for (int off = 32; off > 0; off >>= 1) { s += __shfl_xor(s, off); s2 += __shfl_xor(s2, off); }
    if (lane == 0) {
        float mean = s * (1.f / 384.f);
        float var  = fmaxf(s2 * (1.f / 384.f) - mean * mean, 0.f);
        stats[2 * t]     = mean;
        stats[2 * t + 1] = rsqrtf(var + 1e-5f);
    }
}

// ---------------- weight convert f32 KxN -> bf16 NxK (transposed) ----------------
__global__ __launch_bounds__(256)
void wconv_kernel(const float* __restrict__ W, __hip_bfloat16* __restrict__ Wt,
                  int K, int N, int total)
{
    int idx = blockIdx.x * 256 + threadIdx.x;
    if (idx >= total) return;
    int k = idx / N, n = idx - k * N;
    Wt[(size_t)n * K + k] = f2bf(W[idx]);
}

// ---------------- fused LN1 + roll + window-gather -> winbuf bf16 ----------------
__global__ __launch_bounds__(256)
void ln1_gather_kernel(const float* __restrict__ x,
                       const float* __restrict__ g,
                       const float* __restrict__ bb,
                       __hip_bfloat16* __restrict__ wbuf)
{
    int wrow = blockIdx.x * 4 + (threadIdx.x >> 6);
    int lane = threadIdx.x & 63;
    int bi = wrow / 49, n = wrow - bi * 49;
    int b_ = bi >> 6, wid = bi & 63;
    int wh = wid >> 3, ww = wid & 7;
    int r = n / 7, c = n - (n / 7) * 7;
    int sh = wh * 7 + r + 3; if (sh >= 56) sh -= 56;
    int sw = ww * 7 + c + 3; if (sw >= 56) sw -= 56;
    const float* p = x + (size_t)(b_ * 3136 + sh * 56 + sw) * 384 + lane * 6;
    float v[6];
    float2 v01 = *(const float2*)p;
    float2 v23 = *(const float2*)(p + 2);
    float2 v45 = *(const float2*)(p + 4);
    v[0] = v01.x; v[1] = v01.y; v[2] = v23.x; v[3] = v23.y; v[4] = v45.x; v[5] = v45.y;
    float s = 0.f, s2 = 0.f;
#pragma unroll
    for (int u = 0; u < 6; ++u) { s += v[u]; s2 += v[u] * v[u]; }
#pragma unroll
    for (int off = 32; off > 0; off >>= 1) { s += __shfl_xor(s, off); s2 += __shfl_xor(s2, off); }
    float mean = s * (1.f / 384.f);
    float var  = fmaxf(s2 * (1.f / 384.f) - mean * mean, 0.f);
    float rstd = rsqrtf(var + 1e-5f);
    __hip_bfloat16* dst = wbuf + (size_t)wrow * 384 + lane * 6;
#pragma unroll
    for (int u = 0; u < 6; ++u) {
        int ch = lane * 6 + u;
        dst[u] = f2bf((v[u] - mean) * rstd * g[ch] + bb[ch]);
    }
}

// ---------------- attention: scores + bias/mask + softmax + PV per (win, head) ---
__global__ __launch_bounds__(256)
void attn_kernel(const __hip_bfloat16* __restrict__ qkv,   // chunk-local 12544x1152
                 const float* __restrict__ rel_bias,       // 169 x 12
                 __hip_bfloat16* __restrict__ attn_out,    // global (100352x384)
                 int win_base)
{
    const int wi = blockIdx.x / 12;
    const int nh = blockIdx.x - wi * 12;
    const int gwin = win_base + wi;
    const int wid = gwin & 63;
    const int wh = wid >> 3, ww = wid & 7;
    const int tid = threadIdx.x;

    __shared__ alignas(16) float sQ[49 * 36];   // padded stride 36: conflict-free
    __shared__ alignas(16) float sK[49 * 36];
    __shared__ alignas(16) float sV[49 * 36];
    __shared__ float sS[49 * 49];
    __shared__ float sBias[169];
    __shared__ unsigned char sGrp[49];

    for (int idx = tid; idx < 169; idx += 256) sBias[idx] = rel_bias[idx * 12 + nh];
    if (tid < 49) {
        int r = tid / 7, c = tid - (tid / 7) * 7;
        int gh = (wh == 7) ? ((r < 4) ? 1 : 2) : 0;
        int gw = (ww == 7) ? ((c < 4) ? 1 : 2) : 0;
        sGrp[tid] = (unsigned char)(gh * 3 + gw);
    }
    // load q,k,v (bf16 -> f32 LDS), 588 16B segments
    for (int s = tid; s < 588; s += 256) {
        int which = s / 196, rem = s - which * 196;
        int row = rem >> 2, seg = rem & 3;
        bf16x8 vv = *(const bf16x8*)(qkv + (size_t)(wi * 49 + row) * 1152
                                     + which * 384 + nh * 32 + seg * 8);
        float* dstp = (which == 0 ? sQ : which == 1 ? sK : sV) + row * 36 + seg * 8;
#pragma unroll
        for (int e = 0; e < 8; ++e) dstp[e] = s2f(vv[e]);
    }
    __syncthreads();

    for (int idx = tid; idx < 2401; idx += 256) {
        int i = idx / 49, j = idx - (idx / 49) * 49;
        const float* qp = sQ + i * 36;
        const float* kp = sK + j * 36;
        float acc = 0.f;
#pragma unroll
        for (int d = 0; d < 32; ++d) acc += qp[d] * kp[d];
        int ri = i / 7, ci = i - (i / 7) * 7;
        int rj = j / 7, cj = j - (j / 7) * 7;
        float bias = sBias[(ri - rj + 6) * 13 + (ci - cj + 6)];
        float msk = (sGrp[i] == sGrp[j]) ? 0.f : -100.f;
        sS[idx] = acc * 0.17677669529663689f + bias + msk;
    }
    __syncthreads();

    // wave-parallel softmax: 4 lanes per row
    if (tid < 196) {
        int i = tid >> 2, l4 = tid & 3;
        float mx = -1e30f;
        for (int j = l4; j < 49; j += 4) mx = fmaxf(mx, sS[i * 49 + j]);
        mx = fmaxf(mx, __shfl_xor(mx, 1, 4));
        mx = fmaxf(mx, __shfl_xor(mx, 2, 4));
        float sum = 0.f;
        for (int j = l4; j < 49; j += 4) {
            float e = expf(sS[i * 49 + j] - mx);
            sS[i * 49 + j] = e; sum += e;
        }
        sum += __shfl_xor(sum, 1, 4);
        sum += __shfl_xor(sum, 2, 4);
        float inv = 1.f / sum;
        for (int j = l4; j < 49; j += 4) sS[i * 49 + j] *= inv;
    }
    __syncthreads();

    __hip_bfloat16* dst = attn_out + (size_t)gwin * 49 * 384 + nh * 32;
    for (int idx = tid; idx < 1568; idx += 256) {
        int i = idx >> 5, d = idx & 31;
        const float* sp = sS + i * 49;
        float acc = 0.f;
#pragma unroll
        for (int j = 0; j < 49; ++j) acc += sp[j] * sV[j * 36 + d];
        dst[(size_t)i * 384 + d] = f2bf(acc);
    }
}

// ---------------- MFMA GEMM: 128x128x32 tile, 4 waves, 16x16x32 bf16 -------------
// A: MxK bf16 row-major (chunk-local). Bt: NxK bf16 (pre-transposed weights).
// MODE 0: proj  -> window-reverse+roll scatter + residual(x f32) -> bf16 xmid
// MODE 1: fc1, LN2 applied to A during staging -> gelu -> bf16 hbuf
// MODE 2: fc2 -> gelu -> + residual(bf16) -> f32 out rows [m_base..)
// MODE 3: qkv -> +bias -> bf16 out
template<int MODE>
__global__ __launch_bounds__(256)
void gemm_mfma(const __hip_bfloat16* __restrict__ A,
               const __hip_bfloat16* __restrict__ Bt,
               const float* __restrict__ bias,
               const float* __restrict__ x_in,
               const float* __restrict__ lnst,
               const float* __restrict__ ln_g,
               const float* __restrict__ ln_b,
               const __hip_bfloat16* __restrict__ res,
               __hip_bfloat16* __restrict__ out_h,
               float* __restrict__ out_f,
               int N, int K, int m_base)
{
    __shared__ alignas(16) __hip_bfloat16 As[128 * 40];  // padded: <=2-way conflicts
    __shared__ alignas(16) __hip_bfloat16 Bs[128 * 40];
    const int tid = threadIdx.x;
    const int bm = blockIdx.y, bn = blockIdx.x;
    const int lane = tid & 63;
    const int w = tid >> 6, wr = w >> 1, wc = w & 1;
    const int fr = lane & 15, fq = lane >> 4;

    f32x4 acc[4][4] = {};

    const int r0 = tid >> 2, ks0 = tid & 3;   // seg tid
    const int r1 = r0 + 64;                   // seg tid+256
    const __hip_bfloat16* Aptr0 = A + (size_t)(bm * 128 + r0) * K + ks0 * 8;
    const __hip_bfloat16* Aptr1 = A + (size_t)(bm * 128 + r1) * K + ks0 * 8;
    const __hip_bfloat16* Bptr0 = Bt + (size_t)(bn * 128 + r0) * K + ks0 * 8;
    const __hip_bfloat16* Bptr1 = Bt + (size_t)(bn * 128 + r1) * K + ks0 * 8;

    float lm0 = 0.f, lr0 = 0.f, lm1 = 0.f, lr1 = 0.f;
    if (MODE == 1) {
        lm0 = lnst[2 * (bm * 128 + r0)]; lr0 = lnst[2 * (bm * 128 + r0) + 1];
        lm1 = lnst[2 * (bm * 128 + r1)]; lr1 = lnst[2 * (bm * 128 + r1) + 1];
    }

    for (int kk = 0; kk < K; kk += 32) {
        bf16x8 a0 = *(const bf16x8*)(Aptr0 + kk);
        bf16x8 a1 = *(const bf16x8*)(Aptr1 + kk);
        bf16x8 b0 = *(const bf16x8*)(Bptr0 + kk);
        bf16x8 b1 = *(const bf16x8*)(Bptr1 + kk);
        if (MODE == 1) {
            float4 g0 = *(const float4*)(ln_g + kk + ks0 * 8);
            float4 g1 = *(const float4*)(ln_g + kk + ks0 * 8 + 4);
            float4 c0 = *(const float4*)(ln_b + kk + ks0 * 8);
            float4 c1 = *(const float4*)(ln_b + kk + ks0 * 8 + 4);
            float gv[8] = {g0.x, g0.y, g0.z, g0.w, g1.x, g1.y, g1.z, g1.w};
            float cv[8] = {c0.x, c0.y, c0.z, c0.w, c1.x, c1.y, c1.z, c1.w};
#pragma unroll
            for (int e = 0; e < 8; ++e) {
                a0[e] = f2s((s2f(a0[e]) - lm0) * lr0 * gv[e] + cv[e]);
                a1[e] = f2s((s2f(a1[e]) - lm1) * lr1 * gv[e] + cv[e]);
            }
        }
        __syncthreads();
        *(bf16x8*)&As[r0 * 40 + ks0 * 8] = a0;
        *(bf16x8*)&As[r1 * 40 + ks0 * 8] = a1;
        *(bf16x8*)&Bs[r0 * 40 + ks0 * 8] = b0;
        *(bf16x8*)&Bs[r1 * 40 + ks0 * 8] = b1;
        __syncthreads();
        bf16x8 af[4], bfv[4];
#pragma unroll
        for (int mi = 0; mi < 4; ++mi)
            af[mi] = *(const bf16x8*)&As[(wr * 64 + mi * 16 + fr) * 40 + fq * 8];
#pragma unroll
        for (int ni = 0; ni < 4; ++ni)
            bfv[ni] = *(const bf16x8*)&Bs[(wc * 64 + ni * 16 + fr) * 40 + fq * 8];
#pragma unroll
        for (int mi = 0; mi < 4; ++mi)
#pragma unroll
            for (int ni = 0; ni < 4; ++ni)
                acc[mi][ni] = __builtin_amdgcn_mfma_f32_16x16x32_bf16(
                    af[mi], bfv[ni], acc[mi][ni], 0, 0, 0);
    }

    // epilogue: C row = bm*128 + wr*64 + mi*16 + fq*4 + r; col = bn*128 + wc*64 + ni*16 + fr
    const int mrow0 = bm * 128 + wr * 64;
    const int ncol0 = bn * 128 + wc * 64;
    float bias_v[4];
#pragma unroll
    for (int ni = 0; ni < 4; ++ni) bias_v[ni] = bias[ncol0 + ni * 16 + fr];

#pragma unroll
    for (int mi = 0; mi < 4; ++mi) {
#pragma unroll
        for (int r = 0; r < 4; ++r) {
            int m = mrow0 + mi * 16 + fq * 4 + r;
            if (MODE == 0) {
                int biw = m / 49, n_ = m - biw * 49;
                int b_ = biw >> 6, wid = biw & 63;
                int wh = wid >> 3, ww = wid & 7;
                int rr = n_ / 7, cc = n_ - (n_ / 7) * 7;
                int h = wh * 7 + rr + 3; if (h >= 56) h -= 56;
                int wcol = ww * 7 + cc + 3; if (wcol >= 56) wcol -= 56;
                size_t drow = (size_t)(b_ * 3136 + h * 56 + wcol) * 384;
#pragma unroll
                for (int ni = 0; ni < 4; ++ni) {
                    int nc = ncol0 + ni * 16 + fr;
                    float v = acc[mi][ni][r] + bias_v[ni];
                    out_h[drow + nc] = f2bf(x_in[drow + nc] + v);
                }
            } else if (MODE == 1) {
                size_t o = (size_t)m * N;
#pragma unroll
                for (int ni = 0; ni < 4; ++ni) {
                    int nc = ncol0 + ni * 16 + fr;
                    out_h[o + nc] = f2bf(gelu_exact(acc[mi][ni][r] + bias_v[ni]));
                }
            } else if (MODE == 2) {
                size_t og = (size_t)(m_base + m) * 384;
                size_t ol = (size_t)m * 384;
#pragma unroll
                for (int ni = 0; ni < 4; ++ni) {
                    int nc = ncol0 + ni * 16 + fr;
                    out_f[og + nc] = bf2f(res[ol + nc])
                                   + gelu_exact(acc[mi][ni][r] + bias_v[ni]);
                }
            } else {
                size_t o = (size_t)m * N;
#pragma unroll
                for (int ni = 0; ni < 4; ++ni) {
                    int nc = ncol0 + ni * 16 + fr;
                    out_h[o + nc] = f2bf(acc[mi][ni][r] + bias_v[ni]);
                }
            }
        }
    }
}

extern "C" void kernel_launch(void* const* d_in, const int* in_sizes, int n_in,
                              void* d_out, int out_size, void* d_ws, size_t ws_size,
                              hipStream_t stream)
{
    (void)in_sizes; (void)n_in; (void)out_size; (void)ws_size;
    const float* x      = (const float*)d_in[0];
    const float* ln1_g  = (const float*)d_in[1];
    const float* ln1_b  = (const float*)d_in[2];
    const float* qkv_w  = (const float*)d_in[3];
    const float* qkv_b  = (const float*)d_in[4];
    const float* rel_b  = (const float*)d_in[5];
    const float* proj_w = (const float*)d_in[6];
    const float* proj_b = (const float*)d_in[7];
    const float* ln2_g  = (const float*)d_in[8];
    const float* ln2_b  = (const float*)d_in[9];
    const float* fc1_w  = (const float*)d_in[10];
    const float* fc1_b  = (const float*)d_in[11];
    const float* fc2_w  = (const float*)d_in[12];
    const float* fc2_b  = (const float*)d_in[13];
    float* out = (float*)d_out;

    __hip_bfloat16* aout = (__hip_bfloat16*)d_out;                       // H0
    __hip_bfloat16* wbuf = (__hip_bfloat16*)((char*)d_out + 77070336);   // H1
    __hip_bfloat16* xmid = wbuf;                                         // H1 (after proj)

    char* ws = (char*)d_ws;
    float* ln2s = (float*)ws;                                     //   802,816 B
    __hip_bfloat16* qkv_wt  = (__hip_bfloat16*)(ws + 802816);     //   884,736 B
    __hip_bfloat16* proj_wt = (__hip_bfloat16*)(ws + 1687552);    //   294,912 B
    __hip_bfloat16* fc1_wt  = (__hip_bfloat16*)(ws + 1982464);    // 1,179,648 B
    __hip_bfloat16* fc2_wt  = (__hip_bfloat16*)(ws + 3162112);    // 1,179,648 B
    __hip_bfloat16* qkvbuf  = (__hip_bfloat16*)(ws + 4341760);    // 28,901,376 B (attn)
    __hip_bfloat16* hbuf    = (__hip_bfloat16*)(ws + 4341760);    // 38,535,168 B (mlp)
    __hip_bfloat16* resb    = (__hip_bfloat16*)(ws + 4341760 + 38535168); // 4,816,896 B

    // weight convert + transpose (f32 KxN -> bf16 NxK)
    wconv_kernel<<<1728, 256, 0, stream>>>(qkv_w,  qkv_wt,  384, 1152, 442368);
    wconv_kernel<<<576,  256, 0, stream>>>(proj_w, proj_wt, 384, 384,  147456);
    wconv_kernel<<<2304, 256, 0, stream>>>(fc1_w,  fc1_wt,  384, 1536, 589824);
    wconv_kernel<<<2304, 256, 0, stream>>>(fc2_w,  fc2_wt,  1536, 384, 589824);

    // fused LN1 + roll + window gather -> winbuf (H1)
    ln1_gather_kernel<<<25088, 256, 0, stream>>>(x, ln1_g, ln1_b, wbuf);

    // qkv GEMM + attention, 8 chunks of 256 windows (12544 rows)
    for (int c = 0; c < 8; ++c) {
        size_t mb = (size_t)c * 12544;
        gemm_mfma<3><<<dim3(9, 98), 256, 0, stream>>>(
            wbuf + mb * 384, qkv_wt, qkv_b, nullptr, nullptr, nullptr, nullptr, nullptr,
            qkvbuf, nullptr, 1152, 384, 0);
        attn_kernel<<<3072, 256, 0, stream>>>(qkvbuf, rel_b, aout, c * 256);
    }

    // proj + window-reverse + roll + residual(x) -> xmid (H1, overwrites dead winbuf)
    gemm_mfma<0><<<dim3(3, 784), 256, 0, stream>>>(
        aout, proj_wt, proj_b, x, nullptr, nullptr, nullptr, nullptr,
        xmid, nullptr, 384, 384, 0);

    ln_stats_bf16<<<25088, 256, 0, stream>>>(xmid, ln2s);

    // MLP, 8 chunks of 12544 rows. fc2 residual read directly from xmid is
    // stomp-safe for chunks 0..6 and chunk7's first half; only the last 6272
    // rows self-stomp -> copied to resb first.
    for (int c = 0; c < 8; ++c) {
        size_t mb = (size_t)c * 12544;
        gemm_mfma<1><<<dim3(12, 98), 256, 0, stream>>>(
            xmid + mb * 384, fc1_wt, fc1_b, nullptr, ln2s + 2 * mb, ln2_g, ln2_b, nullptr,
            hbuf, nullptr, 1536, 384, 0);
        if (c < 7) {
            gemm_mfma<2><<<dim3(3, 98), 256, 0, stream>>>(
                hbuf, fc2_wt, fc2_b, nullptr, nullptr, nullptr, nullptr,
                xmid + mb * 384, nullptr, out, 384, 1536, (int)mb);
        } else {
            hipMemcpyAsync(resb, xmid + (size_t)94080 * 384, (size_t)6272 * 384 * 2,
                           hipMemcpyDeviceToDevice, stream);
            gemm_mfma<2><<<dim3(3, 49), 256, 0, stream>>>(
                hbuf, fc2_wt, fc2_b, nullptr, nullptr, nullptr, nullptr,
                xmid + (size_t)87808 * 384, nullptr, out, 384, 1536, 87808);
            gemm_mfma<2><<<dim3(3, 49), 256, 0, stream>>>(
                hbuf + (size_t)6272 * 1536, fc2_wt, fc2_b, nullptr, nullptr, nullptr, nullptr,
                resb, nullptr, out, 384, 1536, 94080);
        }
    }
}